// Round 11
// baseline (185.202 us; speedup 1.0000x reference)
//
#include <hip/hip_runtime.h>
#include <hip/hip_bf16.h>
#include <math.h>

#define HID 128
#define NRAD 6
#define TABN 4096          // nearest-neighbor table rows 0..TABN (row TABN = 0, x>=1 gate)
#define CUTOFF_INV 0.2f
#define MZ 95
#define MZP (MZ + 1)       // +1 sentinel row (index 95, huge-negative -> silu contribution == 0)
#define SENTI (MZ << 13)   // sentinel payload: T1 row 95, ftab row 0
#define PAD 32             // padded-CSR slots per node (one 128B line); overflow -> spill list
#define OVF_CAP 65536
#define FTR 8              // ftab rows computed per block (W3 reuse x8)
#define LOG2E 1.4426950408889634f
#define LN2   0.6931471805599453f

typedef unsigned int uint32;
typedef __attribute__((ext_vector_type(2))) float f2;

// ---------- K0: zero ovfcnt + cnt:=z<<24 (deg in low 24 bits) + pack pos/z into float4 ----------
__global__ void zpack_k(const float* __restrict__ pos, const int* __restrict__ z,
                        float4* __restrict__ pos4, int* __restrict__ cnt,
                        int* __restrict__ ovfcnt, int N) {
    int n = blockIdx.x * 256 + threadIdx.x;
    if (blockIdx.x == 0 && threadIdx.x == 0) *ovfcnt = 0;
    if (n < N) {
        int zn = z[n];
        float4 p;
        p.x = pos[3 * n];
        p.y = pos[3 * n + 1];
        p.z = pos[3 * n + 2];
        p.w = __int_as_float(zn);
        pos4[n] = p;
        cnt[n]  = zn << 24;          // deg counts in low 24 bits (max 16M edges)
    }
}

__device__ __forceinline__ int mk_pl(float4 a, float4 b) {
    float dx = a.x - b.x, dy = a.y - b.y, dz = a.z - b.z;
    float d  = sqrtf(dx * dx + dy * dy + dz * dz);
    float u  = fminf(d * CUTOFF_INV, 1.0f) * (float)TABN;
    int   ti = (int)(u + 0.5f);
    if (ti > TABN) ti = TABN;
    return ti | (__float_as_int(a.w) << 13);
}

// ---------- K1 (fused): bf16 T1(+b_lin)/T2 (+sentinel row) + ftab + edge pass (4 edges/thread) ----------
// T1/T2/ftab stored PRE-SCALED by log2(e); gather evaluates silu in exp2 domain.
__global__ void build1(const float* __restrict__ emb, const float* __restrict__ W_lin,
                       const float* __restrict__ freq, const float* __restrict__ W_rbf,
                       const float* __restrict__ b_rbf, const float* __restrict__ b_lin,
                       const int* __restrict__ ei, const float4* __restrict__ pos4,
                       __hip_bfloat16* __restrict__ Tb, float* __restrict__ ftab,
                       int* __restrict__ cnt, int* __restrict__ payload,
                       int* __restrict__ ovfcnt, int2* __restrict__ ovfbuf,
                       int MAXZ, int E) {
    __shared__ float sh[FTR * HID];
    int h   = threadIdx.x;
    int bid = blockIdx.x;
    int nT  = 2 * (MAXZ + 1);
    int nF  = (TABN + FTR) / FTR;          // 513 blocks cover rows 0..4103 (clamped to TABN)
    if (bid < nT) {
        int zz = bid >> 1, s = bid & 1;
        if (zz == MAXZ) {                  // sentinel row: huge-neg => sigmoid==0 => zero contribution
            Tb[(size_t)(s * (MAXZ + 1) + zz) * HID + h] = __float2bfloat16(-86.5f);
            return;
        }
        sh[h] = emb[zz * HID + h];
        __syncthreads();
        const float* W = W_lin + (size_t)s * HID * HID;
        float acc = (s == 0) ? b_lin[h] : 0.f;   // fold bias into T1
#pragma unroll 8
        for (int k = 0; k < HID; ++k) acc = fmaf(sh[k], W[k * HID + h], acc);
        Tb[(size_t)(s * (MAXZ + 1) + zz) * HID + h] = __float2bfloat16(acc * LOG2E);
    } else if (bid < nT + nF) {
        int t0 = (bid - nT) * FTR;
        for (int r = 0; r < FTR; ++r) {
            int t = t0 + r;
            float rbf[NRAD];
            if (t == 0) {
#pragma unroll
                for (int k = 0; k < NRAD; ++k) rbf[k] = freq[k];   // lim x->0 env*sin(fx)=f
            } else if (t >= TABN) {
#pragma unroll
                for (int k = 0; k < NRAD; ++k) rbf[k] = 0.f;       // envelope gate x>=1
            } else {
                float x  = (float)t / (float)TABN;
                float x2 = x * x, x5 = x2 * x2 * x;
                float env = 1.f / x + x5 * (-28.f + x * (48.f + x * (-21.f)));
#pragma unroll
                for (int k = 0; k < NRAD; ++k) rbf[k] = env * sinf(freq[k] * x);
            }
            float pre = b_rbf[h];
#pragma unroll
            for (int k = 0; k < NRAD; ++k) pre = fmaf(rbf[k], W_rbf[k * HID + h], pre);
            sh[r * HID + h] = pre / (1.f + __expf(-pre));   // precise silu (once per table row)
        }
        __syncthreads();
        const float* W3 = W_lin + (size_t)2 * HID * HID;
        float acc[FTR];
#pragma unroll
        for (int r = 0; r < FTR; ++r) acc[r] = 0.f;
#pragma unroll 4
        for (int k = 0; k < HID; ++k) {
            float w = W3[k * HID + h];          // one load feeds 8 FMAs
#pragma unroll
            for (int r = 0; r < FTR; ++r) acc[r] = fmaf(sh[r * HID + k], w, acc[r]);
        }
        for (int r = 0; r < FTR; ++r) {
            int t = t0 + r;
            if (t <= TABN) ftab[(size_t)t * HID + h] = acc[r] * LOG2E;
        }
    } else {
        // edge pass: 4 edges/thread -- 8 gathers, then 4 atomics, then 4 stores (max MLP)
        int t  = (bid - nT - nF) * HID + h;
        int Eq = (E + 3) >> 2;
        if (t < Eq) {
            int e1 = t + Eq, e2 = t + 2 * Eq, e3 = t + 3 * Eq;
            bool h1 = e1 < E, h2 = e2 < E, h3 = e3 < E;
            int i0 = ei[t],  j0 = ei[E + t];
            int i1 = h1 ? ei[e1] : i0, j1 = h1 ? ei[E + e1] : j0;
            int i2 = h2 ? ei[e2] : i0, j2 = h2 ? ei[E + e2] : j0;
            int i3 = h3 ? ei[e3] : i0, j3 = h3 ? ei[E + e3] : j0;
            float4 a0 = pos4[i0], b0 = pos4[j0];       // 8 independent 16B gathers in flight
            float4 a1 = pos4[i1], b1 = pos4[j1];
            float4 a2 = pos4[i2], b2 = pos4[j2];
            float4 a3 = pos4[i3], b3 = pos4[j3];
            int pl0 = mk_pl(a0, b0), pl1 = mk_pl(a1, b1);
            int pl2 = mk_pl(a2, b2), pl3 = mk_pl(a3, b3);
            // batch the 4 atomics (independent), then the 4 dependent stores
            int r0 =      atomicAdd(&cnt[j0], 1) & 0xFFFFFF;
            int r1 = h1 ? atomicAdd(&cnt[j1], 1) & 0xFFFFFF : 0;
            int r2 = h2 ? atomicAdd(&cnt[j2], 1) & 0xFFFFFF : 0;
            int r3 = h3 ? atomicAdd(&cnt[j3], 1) & 0xFFFFFF : 0;
            if (r0 < PAD) payload[(size_t)j0 * PAD + r0] = pl0;
            else { int o = atomicAdd(ovfcnt, 1); if (o < OVF_CAP) ovfbuf[o] = make_int2(j0, pl0); }
            if (h1) {
                if (r1 < PAD) payload[(size_t)j1 * PAD + r1] = pl1;
                else { int o = atomicAdd(ovfcnt, 1); if (o < OVF_CAP) ovfbuf[o] = make_int2(j1, pl1); }
            }
            if (h2) {
                if (r2 < PAD) payload[(size_t)j2 * PAD + r2] = pl2;
                else { int o = atomicAdd(ovfcnt, 1); if (o < OVF_CAP) ovfbuf[o] = make_int2(j2, pl2); }
            }
            if (h3) {
                if (r3 < PAD) payload[(size_t)j3 * PAD + r3] = pl3;
                else { int o = atomicAdd(ovfcnt, 1); if (o < OVF_CAP) ovfbuf[o] = make_int2(j3, pl3); }
            }
        }
    }
}

// 2^(-x) in one instruction (neg folded as src modifier)
__device__ __forceinline__ float exp2neg(float x) {
    float r; asm("v_exp_f32 %0, -%1" : "=v"(r) : "v"(x)); return r;
}

#define RL(pv_, idx_) __builtin_amdgcn_readlane((pv_), (idx_))

// ftab f2 fragment: SGPR pl -> SALU row offset, + per-lane byte offset
#define FLOAD(pl_) (*(const f2*)((const char*)ftab + (uint32)((((pl_) & 0x1FFF) << 9) + fbyte)))

// LDS T1 bf16-pair fragment (one uint32 per lane): SGPR row base + per-lane index
#define TLA(pl_) sT[((((pl_) >> 13) & 0x7F) << 6) + lane]

// packed silu accumulate for 2 h-values (exp2 domain)
#define COMPUTE(f_, ua_, Bv_, acc_) do {                                       \
    f2 A_, P_, E_, R_;                                                         \
    A_.x = __uint_as_float((ua_) << 16);                                       \
    A_.y = __uint_as_float((ua_) & 0xFFFF0000u);                               \
    P_ = (A_ + Bv_) + f_;                     /* v_pk_add_f32 x2 */            \
    E_.x = exp2neg(P_.x);  E_.y = exp2neg(P_.y);                               \
    E_ = E_ + onev;                           /* 1 + 2^-p */                   \
    R_.x = __builtin_amdgcn_rcpf(E_.x);                                        \
    R_.y = __builtin_amdgcn_rcpf(E_.y);                                        \
    acc_ = __builtin_elementwise_fma(P_, R_, acc_);  /* v_pk_fma_f32 */        \
} while (0)

// ---------- gather: 2 nodes/wave interleaved, pair-level metadata pipeline ----------
__launch_bounds__(1024, 8)
__global__ void gather_k(const int* __restrict__ cnt, const int* __restrict__ payload,
                         const uint32* __restrict__ Tb32, const float* __restrict__ ftab,
                         const int* __restrict__ ovfcnt, const int2* __restrict__ ovfbuf,
                         float* __restrict__ out, int N) {
    __shared__ uint32 sT[MZP * (HID / 2)];       // 24576 B, T1 only (bf16 pairs)
    int tid = threadIdx.x;
    for (int k = tid; k < MZP * (HID / 2); k += 1024) sT[k] = Tb32[k];
    __syncthreads();

    const uint32* T2g = Tb32 + MZP * (HID / 2);  // T2 stays in global (L2-resident)
    int lane = tid & 63;
    int l32  = lane & 31;                        // payload slot mirror (readlane <=34 safe)
    int wv   = __builtin_amdgcn_readfirstlane(tid >> 6);   // uniform wave id 0..15
    uint32 fbyte = (uint32)lane << 3;            // 2 floats per lane in ftab row
    f2 onev; onev.x = 1.f; onev.y = 1.f;
    int nov  = __builtin_amdgcn_readfirstlane(*ovfcnt);
    if (nov > OVF_CAP) nov = OVF_CAP;
    int nW  = gridDim.x << 4;                    // total waves
    int nW2 = nW << 1;

    // pair 0: nodes (nA, nB)
    int nA = (blockIdx.x << 4) + wv;
    int nB = nA + nW;

    // load + resolve pair 0 (exposed once per wave)
    int cvA = 0, cvB = 0, plvA = SENTI, plvB = SENTI;
    if (nA < N) { cvA = __builtin_amdgcn_readfirstlane(cnt[nA]); plvA = payload[(size_t)nA * PAD + l32]; }
    if (nB < N) { cvB = __builtin_amdgcn_readfirstlane(cnt[nB]); plvB = payload[(size_t)nB * PAD + l32]; }
    int degA = cvA & 0xFFFFFF, degB = cvB & 0xFFFFFF;
    int cbA = degA < PAD ? degA : PAD, cbB = degB < PAD ? degB : PAD;
    plvA = (l32 < cbA) ? plvA : SENTI;
    plvB = (l32 < cbB) ? plvB : SENTI;
    uint32 ubA = 0, ubB = 0;
    if (nA < N) ubA = T2g[((((uint32)cvA) >> 24) << 6) + lane];
    if (nB < N) ubB = T2g[((((uint32)cvB) >> 24) << 6) + lane];
    f2 gA00 = FLOAD(RL(plvA, 0));
    f2 gB00 = FLOAD(RL(plvB, 0));

    // pair 1: issue independent metadata
    int nA1 = nA + nW2, nB1 = nB + nW2;
    int cvA1 = 0, cvB1 = 0, plvA1 = SENTI, plvB1 = SENTI;
    if (nA1 < N) { cvA1 = __builtin_amdgcn_readfirstlane(cnt[nA1]); plvA1 = payload[(size_t)nA1 * PAD + l32]; }
    if (nB1 < N) { cvB1 = __builtin_amdgcn_readfirstlane(cnt[nB1]); plvB1 = payload[(size_t)nB1 * PAD + l32]; }

    while (nA < N) {
        // issue pair-2 metadata (independent, one pair-compute of cover)
        int nA2 = nA1 + nW2, nB2 = nB1 + nW2;
        int cvA2 = 0, cvB2 = 0, plvA2 = SENTI, plvB2 = SENTI;
        if (nA2 < N) { cvA2 = __builtin_amdgcn_readfirstlane(cnt[nA2]); plvA2 = payload[(size_t)nA2 * PAD + l32]; }
        if (nB2 < N) { cvB2 = __builtin_amdgcn_readfirstlane(cnt[nB2]); plvB2 = payload[(size_t)nB2 * PAD + l32]; }
        // resolve pair 1 (dependent T2/ftab loads issued now, consumed next iteration)
        int degA1 = cvA1 & 0xFFFFFF, degB1 = cvB1 & 0xFFFFFF;
        int cbA1 = degA1 < PAD ? degA1 : PAD, cbB1 = degB1 < PAD ? degB1 : PAD;
        plvA1 = (l32 < cbA1) ? plvA1 : SENTI;
        plvB1 = (l32 < cbB1) ? plvB1 : SENTI;
        uint32 ubA1 = 0, ubB1 = 0;
        if (nA1 < N) ubA1 = T2g[((((uint32)cvA1) >> 24) << 6) + lane];
        if (nB1 < N) ubB1 = T2g[((((uint32)cvB1) >> 24) << 6) + lane];
        f2 gA01 = FLOAD(RL(plvA1, 0));
        f2 gB01 = FLOAD(RL(plvB1, 0));

        // compute pair 0: two interleaved independent chains
        f2 BvA, BvB;
        BvA.x = __uint_as_float(ubA << 16); BvA.y = __uint_as_float(ubA & 0xFFFF0000u);
        BvB.x = __uint_as_float(ubB << 16); BvB.y = __uint_as_float(ubB & 0xFFFF0000u);
        f2 accA; accA.x = 0.f; accA.y = 0.f;
        f2 accB; accB.x = 0.f; accB.y = 0.f;
        int cbm = cbA > cbB ? cbA : cbB;          // sentinel slots make over-iteration exact 0
        if (cbm > 0) {
            int plA1e = RL(plvA, 1), plB1e = RL(plvB, 1);
            int plA2e = RL(plvA, 2), plB2e = RL(plvB, 2);
            f2 gA0 = gA00, gB0 = gB00;
            f2 gA1 = FLOAD(plA1e), gB1 = FLOAD(plB1e);
            f2 gA2 = FLOAD(plA2e), gB2 = FLOAD(plB2e);
            uint32 uaA0 = TLA(RL(plvA, 0)), uaB0 = TLA(RL(plvB, 0));
            uint32 uaA1 = TLA(plA1e),       uaB1 = TLA(plB1e);
#pragma unroll 2
            for (int k = 0; k < cbm; ++k) {
                int plA3 = RL(plvA, k + 3), plB3 = RL(plvB, k + 3);  // lanes <=34: mirrored, valid
                f2 gA3 = FLOAD(plA3), gB3 = FLOAD(plB3);             // global, 3 iters ahead
                uint32 uaA2 = TLA(plA2e), uaB2 = TLA(plB2e);         // LDS, 2 iters ahead
                COMPUTE(gA0, uaA0, BvA, accA);
                COMPUTE(gB0, uaB0, BvB, accB);
                gA0 = gA1; gA1 = gA2; gA2 = gA3;
                gB0 = gB1; gB1 = gB2; gB2 = gB3;
                uaA0 = uaA1; uaA1 = uaA2;
                uaB0 = uaB1; uaB1 = uaB2;
                plA2e = plA3; plB2e = plB3;
            }
        }
        // overflow edges (deg > PAD): owning wave folds them in (list empty in practice)
        if ((degA > PAD || degB > PAD) && nov > 0) {
            for (int o = 0; o < nov; ++o) {
                int2 v = ovfbuf[o];
                int jn = __builtin_amdgcn_readfirstlane(v.x);
                if (jn == nA || jn == nB) {
                    int pl = __builtin_amdgcn_readfirstlane(v.y);
                    f2 f_ = FLOAD(pl);
                    uint32 ua_ = TLA(pl);
                    if (jn == nA) COMPUTE(f_, ua_, BvA, accA);
                    else          COMPUTE(f_, ua_, BvB, accB);
                }
            }
        }
        float sA = (degA > 0) ? LN2 / (float)degA : 0.0f;   // ln2 folds exp2-domain scale back
        f2 oA; oA.x = accA.x * sA; oA.y = accA.y * sA;
        *(f2*)(out + (size_t)nA * HID + (lane << 1)) = oA;
        if (nB < N) {
            float sB = (degB > 0) ? LN2 / (float)degB : 0.0f;
            f2 oB; oB.x = accB.x * sB; oB.y = accB.y * sB;
            *(f2*)(out + (size_t)nB * HID + (lane << 1)) = oB;
        }

        // shift pair pipeline
        nA = nA1; nB = nB1; nA1 = nA2; nB1 = nB2;
        degA = degA1; degB = degB1; cbA = cbA1; cbB = cbB1;
        plvA = plvA1; plvB = plvB1; ubA = ubA1; ubB = ubB1;
        gA00 = gA01; gB00 = gB01;
        cvA1 = cvA2; cvB1 = cvB2; plvA1 = plvA2; plvB1 = plvB2;
    }
}

// ---------- launch ----------
extern "C" void kernel_launch(void* const* d_in, const int* in_sizes, int n_in,
                              void* d_out, int out_size, void* d_ws, size_t ws_size,
                              hipStream_t stream) {
    const int*   z     = (const int*)d_in[0];
    const float* pos   = (const float*)d_in[1];
    const int*   ei    = (const int*)d_in[2];
    const float* freq  = (const float*)d_in[3];
    const float* emb   = (const float*)d_in[4];
    const float* W_rbf = (const float*)d_in[5];
    const float* b_rbf = (const float*)d_in[6];
    const float* W_lin = (const float*)d_in[7];
    const float* b_lin = (const float*)d_in[8];

    int N    = in_sizes[0];
    int E    = in_sizes[2] / 2;
    int MAXZ = in_sizes[4] / HID;   // 95 == MZ
    float* out = (float*)d_out;

    int N_pad = ((N + 1024) / 1024) * 1024;   // multiple of 1024, strictly > N

    char* ws = (char*)d_ws;
    size_t off = 0;
    auto alloc = [&](size_t bytes) { char* p = ws + off; off = (off + bytes + 255) & ~(size_t)255; return p; };
    int*   cnt     = (int*)alloc((size_t)N_pad * 4);
    int*   ovfcnt  = (int*)alloc(256);
    __hip_bfloat16* Tb = (__hip_bfloat16*)alloc((size_t)2 * (MAXZ + 1) * HID * 2);
    float* ftab    = (float*)alloc((size_t)(TABN + 1) * HID * 4);
    int*   payload = (int*)alloc((size_t)N_pad * PAD * 4);
    int2*  ovfbuf  = (int2*)alloc((size_t)OVF_CAP * 8);
    float4* pos4   = (float4*)alloc((size_t)N_pad * 16);

    // K0: zero ovfcnt + seed cnt with z<<24 + pack {pos, z} into 16B rows
    zpack_k<<<(N + 255) / 256, 256, 0, stream>>>(pos, z, pos4, cnt, ovfcnt, N);

    int Eq = (E + 3) / 4;
    int nBuild = 2 * (MAXZ + 1) + (TABN + FTR) / FTR + (Eq + HID - 1) / HID;
    build1<<<nBuild, HID, 0, stream>>>(emb, W_lin, freq, W_rbf, b_rbf, b_lin,
                                       ei, pos4, Tb, ftab, cnt, payload,
                                       ovfcnt, ovfbuf, MAXZ, E);
    gather_k<<<512, 1024, 0, stream>>>(cnt, payload, (const uint32*)Tb, ftab,
                                       ovfcnt, ovfbuf, out, N);
}

// Round 12
// 178.095 us; speedup vs baseline: 1.0399x; 1.0399x over previous
//
#include <hip/hip_runtime.h>
#include <hip/hip_bf16.h>
#include <math.h>

#define HID 128
#define NRAD 6
#define TABN 4096          // nearest-neighbor table rows 0..TABN (row TABN = 0, x>=1 gate)
#define CUTOFF_INV 0.2f
#define MZ 95
#define MZP (MZ + 1)       // +1 sentinel row (index 95, huge-negative -> silu contribution == 0)
#define SENTI (MZ << 13)   // sentinel payload: T1 row 95, ftab row 0
#define PAD 32             // padded-CSR slots per node (one 128B line); overflow -> spill list
#define OVF_CAP 65536
#define FTR 8              // ftab rows computed per block (W3 reuse x8)
#define LOG2E 1.4426950408889634f
#define LN2   0.6931471805599453f

typedef unsigned int uint32;
typedef __attribute__((ext_vector_type(2))) float f2;

// ---------- K0: zero ovfcnt + cnt:=z<<24 (deg in low 24 bits) + pack pos/z into float4 ----------
__global__ void zpack_k(const float* __restrict__ pos, const int* __restrict__ z,
                        float4* __restrict__ pos4, int* __restrict__ cnt,
                        int* __restrict__ ovfcnt, int N) {
    int n = blockIdx.x * 256 + threadIdx.x;
    if (blockIdx.x == 0 && threadIdx.x == 0) *ovfcnt = 0;
    if (n < N) {
        int zn = z[n];
        float4 p;
        p.x = pos[3 * n];
        p.y = pos[3 * n + 1];
        p.z = pos[3 * n + 2];
        p.w = __int_as_float(zn);
        pos4[n] = p;
        cnt[n]  = zn << 24;          // deg counts in low 24 bits (max 16M edges)
    }
}

__device__ __forceinline__ int mk_pl(float4 a, float4 b) {
    float dx = a.x - b.x, dy = a.y - b.y, dz = a.z - b.z;
    float d  = sqrtf(dx * dx + dy * dy + dz * dz);
    float u  = fminf(d * CUTOFF_INV, 1.0f) * (float)TABN;
    int   ti = (int)(u + 0.5f);
    if (ti > TABN) ti = TABN;
    return ti | (__float_as_int(a.w) << 13);
}

// ---------- K1 (fused): bf16 T1(+b_lin)/T2 (+sentinel row) + ftab + edge pass (1 edge/thread) ----------
// T1/T2/ftab stored PRE-SCALED by log2(e); gather evaluates silu in exp2 domain.
__global__ void build1(const float* __restrict__ emb, const float* __restrict__ W_lin,
                       const float* __restrict__ freq, const float* __restrict__ W_rbf,
                       const float* __restrict__ b_rbf, const float* __restrict__ b_lin,
                       const int* __restrict__ ei, const float4* __restrict__ pos4,
                       __hip_bfloat16* __restrict__ Tb, float* __restrict__ ftab,
                       int* __restrict__ cnt, int* __restrict__ payload,
                       int* __restrict__ ovfcnt, int2* __restrict__ ovfbuf,
                       int MAXZ, int E) {
    __shared__ float sh[FTR * HID];
    int h   = threadIdx.x;
    int bid = blockIdx.x;
    int nT  = 2 * (MAXZ + 1);
    int nF  = (TABN + FTR) / FTR;          // 513 blocks cover rows 0..4103 (clamped to TABN)
    if (bid < nT) {
        int zz = bid >> 1, s = bid & 1;
        if (zz == MAXZ) {                  // sentinel row: huge-neg => sigmoid==0 => zero contribution
            Tb[(size_t)(s * (MAXZ + 1) + zz) * HID + h] = __float2bfloat16(-86.5f);
            return;
        }
        sh[h] = emb[zz * HID + h];
        __syncthreads();
        const float* W = W_lin + (size_t)s * HID * HID;
        float acc = (s == 0) ? b_lin[h] : 0.f;   // fold bias into T1
#pragma unroll 8
        for (int k = 0; k < HID; ++k) acc = fmaf(sh[k], W[k * HID + h], acc);
        Tb[(size_t)(s * (MAXZ + 1) + zz) * HID + h] = __float2bfloat16(acc * LOG2E);
    } else if (bid < nT + nF) {
        int t0 = (bid - nT) * FTR;
        for (int r = 0; r < FTR; ++r) {
            int t = t0 + r;
            float rbf[NRAD];
            if (t == 0) {
#pragma unroll
                for (int k = 0; k < NRAD; ++k) rbf[k] = freq[k];   // lim x->0 env*sin(fx)=f
            } else if (t >= TABN) {
#pragma unroll
                for (int k = 0; k < NRAD; ++k) rbf[k] = 0.f;       // envelope gate x>=1
            } else {
                float x  = (float)t / (float)TABN;
                float x2 = x * x, x5 = x2 * x2 * x;
                float env = 1.f / x + x5 * (-28.f + x * (48.f + x * (-21.f)));
#pragma unroll
                for (int k = 0; k < NRAD; ++k) rbf[k] = env * sinf(freq[k] * x);
            }
            float pre = b_rbf[h];
#pragma unroll
            for (int k = 0; k < NRAD; ++k) pre = fmaf(rbf[k], W_rbf[k * HID + h], pre);
            sh[r * HID + h] = pre / (1.f + __expf(-pre));   // precise silu (once per table row)
        }
        __syncthreads();
        const float* W3 = W_lin + (size_t)2 * HID * HID;
        float acc[FTR];
#pragma unroll
        for (int r = 0; r < FTR; ++r) acc[r] = 0.f;
#pragma unroll 4
        for (int k = 0; k < HID; ++k) {
            float w = W3[k * HID + h];          // one load feeds 8 FMAs
#pragma unroll
            for (int r = 0; r < FTR; ++r) acc[r] = fmaf(sh[r * HID + k], w, acc[r]);
        }
        for (int r = 0; r < FTR; ++r) {
            int t = t0 + r;
            if (t <= TABN) ftab[(size_t)t * HID + h] = acc[r] * LOG2E;
        }
    } else {
        // edge pass: 1 edge/thread (max TLP, ~12 waves/SIMD) -- 2 scattered 16B gathers,
        // atomic rank on cnt (z in bits 24-31), direct padded write
        int e = (bid - nT - nF) * HID + h;
        if (e < E) {
            int i = ei[e];
            int j = ei[E + e];
            float4 a = pos4[i];
            float4 b = pos4[j];
            int pl = mk_pl(a, b);
            int r  = atomicAdd(&cnt[j], 1) & 0xFFFFFF;
            if (r < PAD) {
                payload[(size_t)j * PAD + r] = pl;
            } else {
                int o = atomicAdd(ovfcnt, 1);
                if (o < OVF_CAP) ovfbuf[o] = make_int2(j, pl);
            }
        }
    }
}

// 2^(-x) in one instruction (neg folded as src modifier)
__device__ __forceinline__ float exp2neg(float x) {
    float r; asm("v_exp_f32 %0, -%1" : "=v"(r) : "v"(x)); return r;
}

#define RL(pv_, idx_) __builtin_amdgcn_readlane((pv_), (idx_))

// ftab f2 fragment: SGPR pl -> SALU row offset, + per-lane byte offset
#define FLOAD(pl_) (*(const f2*)((const char*)ftab + (uint32)((((pl_) & 0x1FFF) << 9) + fbyte)))

// LDS T1 bf16-pair fragment (one uint32 per lane): SGPR row base + per-lane index
#define TLA(pl_) sT[((((pl_) >> 13) & 0x7F) << 6) + lane]

// packed silu accumulate for 2 h-values (exp2 domain); Bv = per-node T2 row (hoisted)
#define COMPUTE(f_, ua_) do {                                                  \
    f2 A_, P_, E_, R_;                                                         \
    A_.x = __uint_as_float((ua_) << 16);                                       \
    A_.y = __uint_as_float((ua_) & 0xFFFF0000u);                               \
    P_ = (A_ + Bv) + f_;                      /* v_pk_add_f32 x2 */            \
    E_.x = exp2neg(P_.x);  E_.y = exp2neg(P_.y);                               \
    E_ = E_ + onev;                           /* 1 + 2^-p */                   \
    R_.x = __builtin_amdgcn_rcpf(E_.x);                                        \
    R_.y = __builtin_amdgcn_rcpf(E_.y);                                        \
    acc = __builtin_elementwise_fma(P_, R_, acc);  /* v_pk_fma_f32 */          \
} while (0)

// ---------- gather: 1 node/wave, depth-2 node pipeline + first-edge prefetch (R9 champion) ----------
__launch_bounds__(1024)
__global__ void gather_k(const int* __restrict__ cnt, const int* __restrict__ payload,
                         const uint32* __restrict__ Tb32, const float* __restrict__ ftab,
                         const int* __restrict__ ovfcnt, const int2* __restrict__ ovfbuf,
                         float* __restrict__ out, int N) {
    __shared__ uint32 sT[MZP * (HID / 2)];       // 24576 B, T1 only (bf16 pairs)
    int tid = threadIdx.x;
    for (int k = tid; k < MZP * (HID / 2); k += 1024) sT[k] = Tb32[k];
    __syncthreads();

    const uint32* T2g = Tb32 + MZP * (HID / 2);  // T2 stays in global (L2-resident)
    int lane = tid & 63;
    int l32  = lane & 31;                        // payload slot mirror (readlane <=34 safe)
    int wv   = __builtin_amdgcn_readfirstlane(tid >> 6);   // uniform wave id 0..15
    uint32 fbyte = (uint32)lane << 3;            // 2 floats per lane in ftab row
    f2 onev; onev.x = 1.f; onev.y = 1.f;
    int nov  = __builtin_amdgcn_readfirstlane(*ovfcnt);
    if (nov > OVF_CAP) nov = OVF_CAP;
    int nW = gridDim.x << 4;                     // total waves

    int n  = (blockIdx.x << 4) + wv;             // SGPR node index
    int n1 = n + nW;

    // node n: fully resolved metadata (cnt carries z in bits 24-31, deg in 0-23)
    int cv0 = 0, plv0 = SENTI; uint32 ub0 = 0;
    if (n < N) {
        cv0  = __builtin_amdgcn_readfirstlane(cnt[n]);
        plv0 = payload[(size_t)n * PAD + l32];
    }
    int deg0 = cv0 & 0xFFFFFF;
    int zn0  = ((uint32)cv0) >> 24;
    int cb0  = deg0 < PAD ? deg0 : PAD;
    plv0 = (l32 < cb0) ? plv0 : SENTI;
    if (n < N) ub0 = T2g[(zn0 << 6) + lane];
    f2 g00 = FLOAD(RL(plv0, 0));                 // first-edge ftab prefetch (row 0 if sentinel)

    // node n+1: issue independent metadata
    int cv1 = 0, plv1 = SENTI;
    if (n1 < N) {
        cv1  = __builtin_amdgcn_readfirstlane(cnt[n1]);
        plv1 = payload[(size_t)n1 * PAD + l32];
    }

    while (n < N) {
        int n2 = n1 + nW;
        // issue n+2 metadata (independent loads, 2 node-times of cover)
        int cv2 = 0, plv2 = SENTI;
        if (n2 < N) {
            cv2  = __builtin_amdgcn_readfirstlane(cnt[n2]);
            plv2 = payload[(size_t)n2 * PAD + l32];
        }
        // resolve n+1 now: dependent T2 row + sentinel pad + first-edge ftab prefetch
        int deg1 = cv1 & 0xFFFFFF;
        int zn1  = ((uint32)cv1) >> 24;
        int cb1  = deg1 < PAD ? deg1 : PAD;
        plv1 = (l32 < cb1) ? plv1 : SENTI;
        uint32 ub1 = 0;
        if (n1 < N) ub1 = T2g[(zn1 << 6) + lane];
        f2 g01 = FLOAD(RL(plv1, 0));

        // compute node n (all operands arrived >= 1 node-time ago)
        f2 Bv;
        Bv.x = __uint_as_float(ub0 << 16);
        Bv.y = __uint_as_float(ub0 & 0xFFFF0000u);
        f2 acc; acc.x = 0.f; acc.y = 0.f;
        if (cb0 > 0) {
            f2 g0 = g00;
            int pl1e = RL(plv0, 1), pl2e = RL(plv0, 2);
            f2 g1 = FLOAD(pl1e), g2 = FLOAD(pl2e);
            uint32 ua0 = TLA(RL(plv0, 0));
            uint32 ua1 = TLA(pl1e);
#pragma unroll 4
            for (int k = 0; k < cb0; ++k) {
                int pl3 = RL(plv0, k + 3);               // lanes <=34: mirrored, valid
                f2 g3 = FLOAD(pl3);                      // global, 3 iters ahead
                uint32 ua2 = TLA(pl2e);                  // LDS, 2 iters ahead
                COMPUTE(g0, ua0);                        // current edge
                g0 = g1; g1 = g2; g2 = g3;
                ua0 = ua1; ua1 = ua2;
                pl2e = pl3;
            }
        }
        // overflow edges (deg > PAD): owning wave folds them in (list empty in practice)
        if (deg0 > PAD && nov > 0) {
            for (int o = 0; o < nov; ++o) {
                int2 v = ovfbuf[o];
                int jn = __builtin_amdgcn_readfirstlane(v.x);
                if (jn == n) {
                    int pl = __builtin_amdgcn_readfirstlane(v.y);
                    f2 f_ = FLOAD(pl);
                    uint32 ua_ = TLA(pl);
                    COMPUTE(f_, ua_);
                }
            }
        }
        float s = (deg0 > 0) ? LN2 / (float)deg0 : 0.0f;   // ln2 folds exp2-domain scale back
        f2 o2; o2.x = acc.x * s; o2.y = acc.y * s;
        *(f2*)(out + (size_t)n * HID + (lane << 1)) = o2;  // 512B contiguous row per wave

        // shift node pipeline
        n = n1; n1 = n2;
        deg0 = deg1; cb0 = cb1; plv0 = plv1; ub0 = ub1; g00 = g01;
        cv1 = cv2; plv1 = plv2;
    }
}

// ---------- launch ----------
extern "C" void kernel_launch(void* const* d_in, const int* in_sizes, int n_in,
                              void* d_out, int out_size, void* d_ws, size_t ws_size,
                              hipStream_t stream) {
    const int*   z     = (const int*)d_in[0];
    const float* pos   = (const float*)d_in[1];
    const int*   ei    = (const int*)d_in[2];
    const float* freq  = (const float*)d_in[3];
    const float* emb   = (const float*)d_in[4];
    const float* W_rbf = (const float*)d_in[5];
    const float* b_rbf = (const float*)d_in[6];
    const float* W_lin = (const float*)d_in[7];
    const float* b_lin = (const float*)d_in[8];

    int N    = in_sizes[0];
    int E    = in_sizes[2] / 2;
    int MAXZ = in_sizes[4] / HID;   // 95 == MZ
    float* out = (float*)d_out;

    int N_pad = ((N + 1024) / 1024) * 1024;   // multiple of 1024, strictly > N

    char* ws = (char*)d_ws;
    size_t off = 0;
    auto alloc = [&](size_t bytes) { char* p = ws + off; off = (off + bytes + 255) & ~(size_t)255; return p; };
    int*   cnt     = (int*)alloc((size_t)N_pad * 4);
    int*   ovfcnt  = (int*)alloc(256);
    __hip_bfloat16* Tb = (__hip_bfloat16*)alloc((size_t)2 * (MAXZ + 1) * HID * 2);
    float* ftab    = (float*)alloc((size_t)(TABN + 1) * HID * 4);
    int*   payload = (int*)alloc((size_t)N_pad * PAD * 4);
    int2*  ovfbuf  = (int2*)alloc((size_t)OVF_CAP * 8);
    float4* pos4   = (float4*)alloc((size_t)N_pad * 16);

    // K0: zero ovfcnt + seed cnt with z<<24 + pack {pos, z} into 16B rows
    zpack_k<<<(N + 255) / 256, 256, 0, stream>>>(pos, z, pos4, cnt, ovfcnt, N);

    int nBuild = 2 * (MAXZ + 1) + (TABN + FTR) / FTR + (E + HID - 1) / HID;
    build1<<<nBuild, HID, 0, stream>>>(emb, W_lin, freq, W_rbf, b_rbf, b_lin,
                                       ei, pos4, Tb, ftab, cnt, payload,
                                       ovfcnt, ovfbuf, MAXZ, E);
    gather_k<<<512, 1024, 0, stream>>>(cnt, payload, (const uint32*)Tb, ftab,
                                       ovfcnt, ovfbuf, out, N);
}

// Round 13
// 175.352 us; speedup vs baseline: 1.0562x; 1.0156x over previous
//
#include <hip/hip_runtime.h>
#include <hip/hip_bf16.h>
#include <math.h>

#define HID 128
#define NRAD 6
#define TABN 4096          // nearest-neighbor table rows 0..TABN (row TABN = 0, x>=1 gate)
#define CUTOFF_INV 0.2f
#define MZ 95
#define MZP (MZ + 1)       // +1 sentinel row (index 95, huge-negative -> silu contribution == 0)
#define SENTI (MZ << 13)   // sentinel payload: T1 row 95, ftab row 0
#define PAD 32             // padded-CSR slots per node (one 128B line); overflow -> spill list
#define OVF_CAP 65536
#define FTR 8              // ftab rows computed per block (W3 reuse x8)
#define LOG2E 1.4426950408889634f
#define LN2   0.6931471805599453f

typedef unsigned int uint32;
typedef __attribute__((ext_vector_type(2))) float f2;

// ---------- K0: zero ovfcnt + cnt:=z<<24 (deg in low 24 bits) + pack pos/z into float4 ----------
__global__ void zpack_k(const float* __restrict__ pos, const int* __restrict__ z,
                        float4* __restrict__ pos4, int* __restrict__ cnt,
                        int* __restrict__ ovfcnt, int N) {
    int n = blockIdx.x * 256 + threadIdx.x;
    if (blockIdx.x == 0 && threadIdx.x == 0) *ovfcnt = 0;
    if (n < N) {
        int zn = z[n];
        float4 p;
        p.x = pos[3 * n];
        p.y = pos[3 * n + 1];
        p.z = pos[3 * n + 2];
        p.w = __int_as_float(zn);
        pos4[n] = p;
        cnt[n]  = zn << 24;          // deg counts in low 24 bits (max 16M edges)
    }
}

// ---------- K1 (fused): bf16 T1(+b_lin)/T2 (+sentinel row) + ftab + edge pass (2 edges/thread) ----------
// T1/T2/ftab stored PRE-SCALED by log2(e); gather evaluates silu in exp2 domain.
__global__ void build1(const float* __restrict__ emb, const float* __restrict__ W_lin,
                       const float* __restrict__ freq, const float* __restrict__ W_rbf,
                       const float* __restrict__ b_rbf, const float* __restrict__ b_lin,
                       const int* __restrict__ ei, const float4* __restrict__ pos4,
                       __hip_bfloat16* __restrict__ Tb, float* __restrict__ ftab,
                       int* __restrict__ cnt, int* __restrict__ payload,
                       int* __restrict__ ovfcnt, int2* __restrict__ ovfbuf,
                       int MAXZ, int E) {
    __shared__ float sh[FTR * HID];
    int h   = threadIdx.x;
    int bid = blockIdx.x;
    int nT  = 2 * (MAXZ + 1);
    int nF  = (TABN + FTR) / FTR;          // 513 blocks cover rows 0..4103 (clamped to TABN)
    if (bid < nT) {
        int zz = bid >> 1, s = bid & 1;
        if (zz == MAXZ) {                  // sentinel row: huge-neg => sigmoid==0 => zero contribution
            Tb[(size_t)(s * (MAXZ + 1) + zz) * HID + h] = __float2bfloat16(-86.5f);
            return;
        }
        sh[h] = emb[zz * HID + h];
        __syncthreads();
        const float* W = W_lin + (size_t)s * HID * HID;
        float acc = (s == 0) ? b_lin[h] : 0.f;   // fold bias into T1
#pragma unroll 8
        for (int k = 0; k < HID; ++k) acc = fmaf(sh[k], W[k * HID + h], acc);
        Tb[(size_t)(s * (MAXZ + 1) + zz) * HID + h] = __float2bfloat16(acc * LOG2E);
    } else if (bid < nT + nF) {
        int t0 = (bid - nT) * FTR;
        for (int r = 0; r < FTR; ++r) {
            int t = t0 + r;
            float rbf[NRAD];
            if (t == 0) {
#pragma unroll
                for (int k = 0; k < NRAD; ++k) rbf[k] = freq[k];   // lim x->0 env*sin(fx)=f
            } else if (t >= TABN) {
#pragma unroll
                for (int k = 0; k < NRAD; ++k) rbf[k] = 0.f;       // envelope gate x>=1
            } else {
                float x  = (float)t / (float)TABN;
                float x2 = x * x, x5 = x2 * x2 * x;
                float env = 1.f / x + x5 * (-28.f + x * (48.f + x * (-21.f)));
#pragma unroll
                for (int k = 0; k < NRAD; ++k) rbf[k] = env * sinf(freq[k] * x);
            }
            float pre = b_rbf[h];
#pragma unroll
            for (int k = 0; k < NRAD; ++k) pre = fmaf(rbf[k], W_rbf[k * HID + h], pre);
            sh[r * HID + h] = pre / (1.f + __expf(-pre));   // precise silu (once per table row)
        }
        __syncthreads();
        const float* W3 = W_lin + (size_t)2 * HID * HID;
        float acc[FTR];
#pragma unroll
        for (int r = 0; r < FTR; ++r) acc[r] = 0.f;
#pragma unroll 4
        for (int k = 0; k < HID; ++k) {
            float w = W3[k * HID + h];          // one load feeds 8 FMAs
#pragma unroll
            for (int r = 0; r < FTR; ++r) acc[r] = fmaf(sh[r * HID + k], w, acc[r]);
        }
        for (int r = 0; r < FTR; ++r) {
            int t = t0 + r;
            if (t <= TABN) ftab[(size_t)t * HID + h] = acc[r] * LOG2E;
        }
    } else {
        // edge pass: 2 edges/thread, 2 scattered 16B gathers each, atomic rank + padded scatter
        int t  = (bid - nT - nF) * HID + h;
        int Eh = (E + 1) >> 1;
        if (t < Eh) {
            int  e1   = t + Eh;
            bool has1 = e1 < E;
            int i0 = ei[t],  j0 = ei[E + t];
            int i1 = has1 ? ei[e1] : i0, j1 = has1 ? ei[E + e1] : j0;
            float4 a0 = pos4[i0], b0 = pos4[j0];         // 4 independent 16B gathers in flight
            float4 a1 = pos4[i1], b1 = pos4[j1];

            float dx0 = a0.x - b0.x, dy0 = a0.y - b0.y, dz0 = a0.z - b0.z;
            float d0  = sqrtf(dx0 * dx0 + dy0 * dy0 + dz0 * dz0);
            float u0  = fminf(d0 * CUTOFF_INV, 1.0f) * (float)TABN;
            int   ti0 = (int)(u0 + 0.5f);
            if (ti0 > TABN) ti0 = TABN;
            int pl0 = ti0 | (__float_as_int(a0.w) << 13);
            int r0  = atomicAdd(&cnt[j0], 1) & 0xFFFFFF;   // rank (z lives in bits 24-31)
            if (r0 < PAD) payload[(size_t)j0 * PAD + r0] = pl0;
            else { int o = atomicAdd(ovfcnt, 1); if (o < OVF_CAP) ovfbuf[o] = make_int2(j0, pl0); }

            if (has1) {
                float dx1 = a1.x - b1.x, dy1 = a1.y - b1.y, dz1 = a1.z - b1.z;
                float d1  = sqrtf(dx1 * dx1 + dy1 * dy1 + dz1 * dz1);
                float u1  = fminf(d1 * CUTOFF_INV, 1.0f) * (float)TABN;
                int   ti1 = (int)(u1 + 0.5f);
                if (ti1 > TABN) ti1 = TABN;
                int pl1 = ti1 | (__float_as_int(a1.w) << 13);
                int r1  = atomicAdd(&cnt[j1], 1) & 0xFFFFFF;
                if (r1 < PAD) payload[(size_t)j1 * PAD + r1] = pl1;
                else { int o = atomicAdd(ovfcnt, 1); if (o < OVF_CAP) ovfbuf[o] = make_int2(j1, pl1); }
            }
        }
    }
}

// 2^(-x) in one instruction (neg folded as src modifier)
__device__ __forceinline__ float exp2neg(float x) {
    float r; asm("v_exp_f32 %0, -%1" : "=v"(r) : "v"(x)); return r;
}

#define RL(pv_, idx_) __builtin_amdgcn_readlane((pv_), (idx_))

// ftab f2 fragment: SGPR pl -> SALU row offset, + per-lane byte offset
#define FLOAD(pl_) (*(const f2*)((const char*)ftab + (uint32)((((pl_) & 0x1FFF) << 9) + fbyte)))

// LDS T1 bf16-pair fragment (one uint32 per lane): SGPR row base + per-lane index
#define TLA(pl_) sT[((((pl_) >> 13) & 0x7F) << 6) + lane]

// packed silu accumulate for 2 h-values (exp2 domain); Bv = per-node T2 row (hoisted)
#define COMPUTE(f_, ua_) do {                                                  \
    f2 A_, P_, E_, R_;                                                         \
    A_.x = __uint_as_float((ua_) << 16);                                       \
    A_.y = __uint_as_float((ua_) & 0xFFFF0000u);                               \
    P_ = (A_ + Bv) + f_;                      /* v_pk_add_f32 x2 */            \
    E_.x = exp2neg(P_.x);  E_.y = exp2neg(P_.y);                               \
    E_ = E_ + onev;                           /* 1 + 2^-p */                   \
    R_.x = __builtin_amdgcn_rcpf(E_.x);                                        \
    R_.y = __builtin_amdgcn_rcpf(E_.y);                                        \
    acc = __builtin_elementwise_fma(P_, R_, acc);  /* v_pk_fma_f32 */          \
} while (0)

// ---------- gather: 1 node/wave, depth-2 node pipeline + first-edge prefetch ----------
__launch_bounds__(1024)
__global__ void gather_k(const int* __restrict__ cnt, const int* __restrict__ payload,
                         const uint32* __restrict__ Tb32, const float* __restrict__ ftab,
                         const int* __restrict__ ovfcnt, const int2* __restrict__ ovfbuf,
                         float* __restrict__ out, int N) {
    __shared__ uint32 sT[MZP * (HID / 2)];       // 24576 B, T1 only (bf16 pairs)
    int tid = threadIdx.x;
    for (int k = tid; k < MZP * (HID / 2); k += 1024) sT[k] = Tb32[k];
    __syncthreads();

    const uint32* T2g = Tb32 + MZP * (HID / 2);  // T2 stays in global (L2-resident)
    int lane = tid & 63;
    int l32  = lane & 31;                        // payload slot mirror (readlane <=34 safe)
    int wv   = __builtin_amdgcn_readfirstlane(tid >> 6);   // uniform wave id 0..15
    uint32 fbyte = (uint32)lane << 3;            // 2 floats per lane in ftab row
    f2 onev; onev.x = 1.f; onev.y = 1.f;
    int nov  = __builtin_amdgcn_readfirstlane(*ovfcnt);
    if (nov > OVF_CAP) nov = OVF_CAP;
    int nW = gridDim.x << 4;                     // total waves

    int n  = (blockIdx.x << 4) + wv;             // SGPR node index
    int n1 = n + nW;

    // node n: fully resolved metadata (cnt carries z in bits 24-31, deg in 0-23)
    int cv0 = 0, plv0 = SENTI; uint32 ub0 = 0;
    if (n < N) {
        cv0  = __builtin_amdgcn_readfirstlane(cnt[n]);
        plv0 = payload[(size_t)n * PAD + l32];
    }
    int deg0 = cv0 & 0xFFFFFF;
    int zn0  = ((uint32)cv0) >> 24;
    int cb0  = deg0 < PAD ? deg0 : PAD;
    plv0 = (l32 < cb0) ? plv0 : SENTI;
    if (n < N) ub0 = T2g[(zn0 << 6) + lane];
    f2 g00 = FLOAD(RL(plv0, 0));                 // first-edge ftab prefetch (row 0 if sentinel)

    // node n+1: issue independent metadata
    int cv1 = 0, plv1 = SENTI;
    if (n1 < N) {
        cv1  = __builtin_amdgcn_readfirstlane(cnt[n1]);
        plv1 = payload[(size_t)n1 * PAD + l32];
    }

    while (n < N) {
        int n2 = n1 + nW;
        // issue n+2 metadata (independent loads, 2 node-times of cover)
        int cv2 = 0, plv2 = SENTI;
        if (n2 < N) {
            cv2  = __builtin_amdgcn_readfirstlane(cnt[n2]);
            plv2 = payload[(size_t)n2 * PAD + l32];
        }
        // resolve n+1 now: dependent T2 row + sentinel pad + first-edge ftab prefetch
        int deg1 = cv1 & 0xFFFFFF;
        int zn1  = ((uint32)cv1) >> 24;
        int cb1  = deg1 < PAD ? deg1 : PAD;
        plv1 = (l32 < cb1) ? plv1 : SENTI;
        uint32 ub1 = 0;
        if (n1 < N) ub1 = T2g[(zn1 << 6) + lane];
        f2 g01 = FLOAD(RL(plv1, 0));

        // compute node n (all operands arrived >= 1 node-time ago)
        f2 Bv;
        Bv.x = __uint_as_float(ub0 << 16);
        Bv.y = __uint_as_float(ub0 & 0xFFFF0000u);
        f2 acc; acc.x = 0.f; acc.y = 0.f;
        if (cb0 > 0) {
            f2 g0 = g00;
            int pl1e = RL(plv0, 1), pl2e = RL(plv0, 2);
            f2 g1 = FLOAD(pl1e), g2 = FLOAD(pl2e);
            uint32 ua0 = TLA(RL(plv0, 0));
            uint32 ua1 = TLA(pl1e);
#pragma unroll 4
            for (int k = 0; k < cb0; ++k) {
                int pl3 = RL(plv0, k + 3);               // lanes <=34: mirrored, valid
                f2 g3 = FLOAD(pl3);                      // global, 3 iters ahead
                uint32 ua2 = TLA(pl2e);                  // LDS, 2 iters ahead
                COMPUTE(g0, ua0);                        // current edge
                g0 = g1; g1 = g2; g2 = g3;
                ua0 = ua1; ua1 = ua2;
                pl2e = pl3;
            }
        }
        // overflow edges (deg > PAD): owning wave folds them in (list empty in practice)
        if (deg0 > PAD && nov > 0) {
            for (int o = 0; o < nov; ++o) {
                int2 v = ovfbuf[o];
                int jn = __builtin_amdgcn_readfirstlane(v.x);
                if (jn == n) {
                    int pl = __builtin_amdgcn_readfirstlane(v.y);
                    f2 f_ = FLOAD(pl);
                    uint32 ua_ = TLA(pl);
                    COMPUTE(f_, ua_);
                }
            }
        }
        float s = (deg0 > 0) ? LN2 / (float)deg0 : 0.0f;   // ln2 folds exp2-domain scale back
        f2 o2; o2.x = acc.x * s; o2.y = acc.y * s;
        *(f2*)(out + (size_t)n * HID + (lane << 1)) = o2;  // 512B contiguous row per wave

        // shift node pipeline
        n = n1; n1 = n2;
        deg0 = deg1; cb0 = cb1; plv0 = plv1; ub0 = ub1; g00 = g01;
        cv1 = cv2; plv1 = plv2;
    }
}

// ---------- launch ----------
extern "C" void kernel_launch(void* const* d_in, const int* in_sizes, int n_in,
                              void* d_out, int out_size, void* d_ws, size_t ws_size,
                              hipStream_t stream) {
    const int*   z     = (const int*)d_in[0];
    const float* pos   = (const float*)d_in[1];
    const int*   ei    = (const int*)d_in[2];
    const float* freq  = (const float*)d_in[3];
    const float* emb   = (const float*)d_in[4];
    const float* W_rbf = (const float*)d_in[5];
    const float* b_rbf = (const float*)d_in[6];
    const float* W_lin = (const float*)d_in[7];
    const float* b_lin = (const float*)d_in[8];

    int N    = in_sizes[0];
    int E    = in_sizes[2] / 2;
    int MAXZ = in_sizes[4] / HID;   // 95 == MZ
    float* out = (float*)d_out;

    int N_pad = ((N + 1024) / 1024) * 1024;   // multiple of 1024, strictly > N

    char* ws = (char*)d_ws;
    size_t off = 0;
    auto alloc = [&](size_t bytes) { char* p = ws + off; off = (off + bytes + 255) & ~(size_t)255; return p; };
    int*   cnt     = (int*)alloc((size_t)N_pad * 4);
    int*   ovfcnt  = (int*)alloc(256);
    __hip_bfloat16* Tb = (__hip_bfloat16*)alloc((size_t)2 * (MAXZ + 1) * HID * 2);
    float* ftab    = (float*)alloc((size_t)(TABN + 1) * HID * 4);
    int*   payload = (int*)alloc((size_t)N_pad * PAD * 4);
    int2*  ovfbuf  = (int2*)alloc((size_t)OVF_CAP * 8);
    float4* pos4   = (float4*)alloc((size_t)N_pad * 16);

    // K0: zero ovfcnt + seed cnt with z<<24 + pack {pos, z} into 16B rows
    zpack_k<<<(N + 255) / 256, 256, 0, stream>>>(pos, z, pos4, cnt, ovfcnt, N);

    int Eh = (E + 1) / 2;
    int nBuild = 2 * (MAXZ + 1) + (TABN + FTR) / FTR + (Eh + HID - 1) / HID;
    build1<<<nBuild, HID, 0, stream>>>(emb, W_lin, freq, W_rbf, b_rbf, b_lin,
                                       ei, pos4, Tb, ftab, cnt, payload,
                                       ovfcnt, ovfbuf, MAXZ, E);
    gather_k<<<512, 1024, 0, stream>>>(cnt, payload, (const uint32*)Tb, ftab,
                                       ovfcnt, ovfbuf, out, N);
}